// Round 10
// baseline (239.733 us; speedup 1.0000x reference)
//
#include <hip/hip_runtime.h>
#include <hip/hip_bf16.h>

#define BB 2
#define LL 5
#define HH 48
#define WW 48
#define CC 256
#define MM 8
#define DD 32
#define HWW (HH*WW)        // 2304
#define NTOK (BB*LL*HWW)   // 23040
#define INNER 256
#define NOUT 1280          // qa(512) | k(256) | vm(512)
#define SCALE_ATT 0.17677669529663687f

typedef __hip_bfloat16 bf16;
typedef short short8 __attribute__((ext_vector_type(8)));
typedef float f32x4  __attribute__((ext_vector_type(4)));

__device__ __forceinline__ float b2f(bf16 v){ return __bfloat162float(v); }
__device__ __forceinline__ bf16 f2b(float v){ return __float2bfloat16(v); }
__device__ __forceinline__ short f2s(float v){
  bf16 h = __float2bfloat16(v);
  return *reinterpret_cast<short*>(&h);
}
__device__ __forceinline__ float s2f(short s){
  return __uint_as_float(((unsigned)(unsigned short)s)<<16);
}

// ---------------------------------------------------------------- LN stats
__global__ __launch_bounds__(256) void ln_stats_kernel(
    const float* __restrict__ x, float* __restrict__ mu, float* __restrict__ rstd)
{
  int tok  = blockIdx.x*4 + (threadIdx.x>>6);
  int lane = threadIdx.x & 63;
  const float4* xr = (const float4*)(x + (size_t)tok*CC);
  float4 v = xr[lane];
  float s  = v.x + v.y + v.z + v.w;
  float sq = v.x*v.x + v.y*v.y + v.z*v.z + v.w*v.w;
  #pragma unroll
  for(int off=32; off>=1; off>>=1){
    s  += __shfl_xor(s,  off, 64);
    sq += __shfl_xor(sq, off, 64);
  }
  if(lane==0){
    float m   = s  * (1.f/CC);
    float var = sq * (1.f/CC) - m*m;
    mu[tok]   = m;
    rstd[tok] = rsqrtf(var + 1e-5f);
  }
}

// ------------------------------------------------- composite weight build
__global__ __launch_bounds__(256) void wcomp_kernel(
    const float* __restrict__ qw, const float* __restrict__ qb,
    const float* __restrict__ kw, const float* __restrict__ kb,
    const float* __restrict__ vw, const float* __restrict__ vb,
    const float* __restrict__ ra, const float* __restrict__ rm,
    bf16* __restrict__ W_all, float* __restrict__ b_all)
{
  int bid = blockIdx.x;
  int t = bid / 320, nb = bid % 320;
  int tid = threadIdx.x;
  int wv = tid>>6, lane = tid&63;
  int n = nb*4 + wv;

  float a0=0.f,a1=0.f,a2=0.f,a3=0.f, bias=0.f;
  if(n < 512 || n >= 768){
    bool isq = (n < 512);
    int nr = isq ? n : n-768;
    int s = nr>>8, mdp = nr&255, m = mdp>>5, dp = mdp&31;
    int r = isq ? (2*t+s) : (2*s+t);
    const float* rel  = (isq ? ra : rm) + ((size_t)r*MM + m)*DD*DD + dp;     // [p] stride DD
    const float* wrow = (isq ? qw : vw) + (size_t)t*INNER*CC + (size_t)m*DD*CC;
    const float* brow = (isq ? qb : vb) + t*INNER + m*DD;
    #pragma unroll
    for(int p=0;p<DD;p++){
      float rv = rel[p*DD];
      float4 w4 = *(const float4*)(wrow + p*CC + lane*4);
      a0 += w4.x*rv; a1 += w4.y*rv; a2 += w4.z*rv; a3 += w4.w*rv;
      bias += brow[p]*rv;
    }
  } else {
    int o = n - 512;
    float4 w4 = *(const float4*)(kw + (size_t)t*INNER*CC + (size_t)o*CC + lane*4);
    a0=w4.x; a1=w4.y; a2=w4.z; a3=w4.w;
    bias = kb[t*INNER + o];
  }
  bf16* dst = W_all + ((size_t)t*NOUT + n)*CC + lane*4;
  dst[0]=f2b(a0); dst[1]=f2b(a1); dst[2]=f2b(a2); dst[3]=f2b(a3);
  if(lane==0) b_all[t*NOUT + n] = bias;
}

// ------------------------------------------------------------ qa/k/vm GEMM (MFMA)
// grid (5, 18, 10): x = 256-col pair tile, y = 128-row tile, z = (b,l)
// A staged once per K-chunk feeds 2 column tiles (64 MFMA / barrier pair).
__global__ __launch_bounds__(256) void qkvm_gemm_kernel(
    const float* __restrict__ x,  const float* __restrict__ pe,
    const float* __restrict__ mu, const float* __restrict__ rstd,
    const float* __restrict__ lnw, const float* __restrict__ lnb,
    const bf16* __restrict__ W_all, const float* __restrict__ b_all,
    bf16* __restrict__ qkvm)
{
  int g = blockIdx.z;
  int t = (int)pe[(size_t)g*HWW*3 + 2];
  int o_base = blockIdx.x * 256;
  const bf16*  wsel = W_all + ((size_t)t*NOUT + o_base)*CC;
  const float* bsel = b_all + t*NOUT;
  int row_base = blockIdx.y*128;
  int tid = threadIdx.x;
  int tokbase = g*HWW + row_base;

  __shared__ __align__(16) short A_s[128*64];
  __shared__ __align__(16) short B_s[256*64];

  int wv = tid>>6, lane = tid&63;
  int wr = wv>>1, wc = wv&1;
  int l16 = lane&15, l4 = lane>>4;
  int kc = tid & 7;            // fixed k-chunk (8 elems) for staging
  int rsub = tid >> 3;         // 0..31

  f32x4 acc[2][4][4];
  #pragma unroll
  for(int c=0;c<2;c++)
    #pragma unroll
    for(int i=0;i<4;i++)
      #pragma unroll
      for(int j=0;j<4;j++) acc[c][i][j] = (f32x4){0.f,0.f,0.f,0.f};

  for(int kk=0; kk<CC; kk+=64){
    if(kk) __syncthreads();
    // ---- stage A (apply LayerNorm, f32 -> bf16), swizzled
    float4 w0 = *(const float4*)(lnw + kk + kc*8);
    float4 w1 = *(const float4*)(lnw + kk + kc*8 + 4);
    float4 c0 = *(const float4*)(lnb + kk + kc*8);
    float4 c1 = *(const float4*)(lnb + kk + kc*8 + 4);
    #pragma unroll
    for(int tt=0; tt<4; tt++){
      int row = rsub + tt*32;
      int tok = tokbase + row;
      float m = mu[tok], rs = rstd[tok];
      const float4* src = (const float4*)(x + (size_t)tok*CC + kk + kc*8);
      float4 xa = src[0], xb = src[1];
      short8 pk;
      pk[0]=f2s((xa.x-m)*rs*w0.x+c0.x); pk[1]=f2s((xa.y-m)*rs*w0.y+c0.y);
      pk[2]=f2s((xa.z-m)*rs*w0.z+c0.z); pk[3]=f2s((xa.w-m)*rs*w0.w+c0.w);
      pk[4]=f2s((xb.x-m)*rs*w1.x+c1.x); pk[5]=f2s((xb.y-m)*rs*w1.y+c1.y);
      pk[6]=f2s((xb.z-m)*rs*w1.z+c1.z); pk[7]=f2s((xb.w-m)*rs*w1.w+c1.w);
      int el = (row*64 + kc*8) ^ ((row&7)<<3);
      *reinterpret_cast<short8*>(&A_s[el]) = pk;
    }
    // ---- stage B: 256 n-rows (2 col tiles), bf16 direct copy, swizzled
    #pragma unroll
    for(int tt=0; tt<8; tt++){
      int n = rsub + tt*32;
      short8 pk = *reinterpret_cast<const short8*>(wsel + (size_t)n*CC + kk + kc*8);
      int el = (n*64 + kc*8) ^ ((n&7)<<3);
      *reinterpret_cast<short8*>(&B_s[el]) = pk;
    }
    __syncthreads();
    // ---- 2 x k32 MFMA rounds x 2 col tiles
    #pragma unroll
    for(int ks=0; ks<2; ks++){
      short8 af[4];
      #pragma unroll
      for(int fr=0; fr<4; fr++){
        int row = wr*64 + fr*16 + l16;
        int el = (row*64 + ks*32 + l4*8) ^ ((row&7)<<3);
        af[fr] = *reinterpret_cast<const short8*>(&A_s[el]);
      }
      #pragma unroll
      for(int ct=0; ct<2; ct++){
        short8 bfr[4];
        #pragma unroll
        for(int fc=0; fc<4; fc++){
          int n = ct*128 + wc*64 + fc*16 + l16;
          int el = (n*64 + ks*32 + l4*8) ^ ((n&7)<<3);
          bfr[fc] = *reinterpret_cast<const short8*>(&B_s[el]);
        }
        #pragma unroll
        for(int fr=0; fr<4; fr++)
          #pragma unroll
          for(int fc=0; fc<4; fc++)
            acc[ct][fr][fc] = __builtin_amdgcn_mfma_f32_16x16x32_bf16(af[fr], bfr[fc], acc[ct][fr][fc], 0,0,0);
      }
    }
  }
  // ---- epilogue: bias + store bf16
  #pragma unroll
  for(int ct=0; ct<2; ct++){
    #pragma unroll
    for(int fr=0; fr<4; fr++){
      #pragma unroll
      for(int fc=0; fc<4; fc++){
        int ocol = o_base + ct*128 + wc*64 + fc*16 + l16;
        float bias = bsel[ocol];
        #pragma unroll
        for(int r=0; r<4; r++){
          int row = row_base + wr*64 + fr*16 + l4*4 + r;
          qkvm[((size_t)g*HWW + row)*NOUT + ocol] = f2b(acc[ct][fr][fc][r] + bias);
        }
      }
    }
  }
}

// ------------------------------------------------------------ attention lite
// grid = B*HWW = 4608 blocks; block 256 thr; half-wave (32 lanes = d) = one head.
// All global I/O staged through LDS with short8 (16B/lane) coalescing.
__global__ __launch_bounds__(256) void attn_lite_kernel(
    const bf16* __restrict__ qkvm, const float* __restrict__ pe,
    const int*  __restrict__ mask, bf16* __restrict__ attn_out)
{
  int pix = blockIdx.x;
  int b = pix / HWW, hw = pix - b*HWW;
  int tid = threadIdx.x;
  int m = tid>>5, d = tid&31;

  __shared__ __align__(16) short lds16[LL*NOUT];   // 12800 B
  __shared__ int st[LL];
  __shared__ unsigned mbS;
  if(tid==0) mbS = 0u;
  if(tid<LL) st[tid] = (int)pe[(size_t)(b*LL+tid)*HWW*3 + 2];
  // ---- stage 5 x 1280 bf16 rows, coalesced short8
  #pragma unroll
  for(int i=0;i<4;i++){
    int idx = tid + i*256;
    if(idx < 800){
      int l = idx/160, c = idx - l*160;
      *reinterpret_cast<short8*>(&lds16[l*NOUT + c*8]) =
        *reinterpret_cast<const short8*>(qkvm + ((size_t)(b*LL+l)*HWW + hw)*NOUT + c*8);
    }
  }
  const int* mrow = mask + ((size_t)b*HWW + hw)*25;
  if(tid<25 && mrow[tid]==0) atomicOr(&mbS, 1u<<tid);
  __syncthreads();
  unsigned mb = mbS;

  float qa[LL][2], kv[LL], vm[LL][2];
  #pragma unroll
  for(int l=0;l<LL;l++){
    int base = l*NOUT + m*DD + d;
    qa[l][0] = s2f(lds16[base]);
    qa[l][1] = s2f(lds16[base+256]);
    kv[l]    = s2f(lds16[base+512]);
    vm[l][0] = s2f(lds16[base+768]);
    vm[l][1] = s2f(lds16[base+1024]);
  }

  float p[LL][LL];
  #pragma unroll
  for(int i=0;i<LL;i++){
    #pragma unroll
    for(int j=0;j<LL;j++){
      int stj = st[j];
      float part = (stj ? qa[i][1] : qa[i][0]) * kv[j];
      #pragma unroll
      for(int off=16; off>=1; off>>=1) part += __shfl_xor(part, off, 32);
      p[i][j] = (mb & (1u<<(i*5+j))) ? -1e9f : part*SCALE_ATT;
    }
  }
  float oreg[LL];
  #pragma unroll
  for(int i=0;i<LL;i++){
    float mx = p[i][0];
    #pragma unroll
    for(int j=1;j<LL;j++) mx = fmaxf(mx, p[i][j]);
    float ssum = 0.f;
    #pragma unroll
    for(int j=0;j<LL;j++){ p[i][j] = __expf(p[i][j]-mx); ssum += p[i][j]; }
    float inv = 1.f/ssum;
    int sti = st[i];
    float o = 0.f;
    #pragma unroll
    for(int j=0;j<LL;j++) o += p[i][j] * (sti ? vm[j][1] : vm[j][0]);
    oreg[i] = o * inv;
  }
  // ---- stage output via LDS, coalesced short8 store
  __syncthreads();               // all register reads of lds16 complete
  #pragma unroll
  for(int i=0;i<LL;i++) lds16[i*CC + m*DD + d] = f2s(oreg[i]);
  __syncthreads();
  if(tid < 160){
    int l = tid >> 5, c = tid & 31;
    *reinterpret_cast<short8*>(attn_out + (((size_t)b*HWW + hw)*LL + l)*CC + c*8) =
      *reinterpret_cast<const short8*>(&lds16[l*CC + c*8]);
  }
}

// ------------------------------------------------------- output projection (MFMA)
// grid (2, 18, 10): x = 128-col tile, y = 128-row tile, z = (b,l)
__global__ __launch_bounds__(256) void out_gemm_kernel(
    const bf16* __restrict__ attn_out, const float* __restrict__ pe,
    const float* __restrict__ aw, const float* __restrict__ ab,
    float* __restrict__ out)
{
  int g = blockIdx.z; int b = g/LL, l = g%LL;
  int t = (int)pe[(size_t)g*HWW*3 + 2];
  int o_base = blockIdx.x*128;
  int row_base = blockIdx.y*128;
  int tid = threadIdx.x;
  const float* wsel = aw + ((size_t)t*CC + o_base)*CC;

  __shared__ __align__(16) short A_s[128*64];
  __shared__ __align__(16) short B_s[128*64];

  int wv = tid>>6, lane = tid&63;
  int wr = wv>>1, wc = wv&1;
  int l16 = lane&15, l4 = lane>>4;
  int kc = tid & 7;
  int rsub = tid >> 3;

  f32x4 acc[4][4];
  #pragma unroll
  for(int i=0;i<4;i++)
    #pragma unroll
    for(int j=0;j<4;j++) acc[i][j] = (f32x4){0.f,0.f,0.f,0.f};

  for(int kk=0; kk<CC; kk+=64){
    if(kk) __syncthreads();
    // ---- stage A (bf16 source, direct 16B copy), swizzled
    #pragma unroll
    for(int tt=0; tt<4; tt++){
      int row = rsub + tt*32;
      short8 pk = *reinterpret_cast<const short8*>(
          attn_out + (((size_t)(b*HWW) + row_base + row)*LL + l)*CC + kk + kc*8);
      int el = (row*64 + kc*8) ^ ((row&7)<<3);
      *reinterpret_cast<short8*>(&A_s[el]) = pk;
    }
    // ---- stage B (weights f32 -> bf16), swizzled
    #pragma unroll
    for(int tt=0; tt<4; tt++){
      int n = rsub + tt*32;
      const float4* src = (const float4*)(wsel + (size_t)n*CC + kk + kc*8);
      float4 ba = src[0], bb = src[1];
      short8 pk;
      pk[0]=f2s(ba.x); pk[1]=f2s(ba.y); pk[2]=f2s(ba.z); pk[3]=f2s(ba.w);
      pk[4]=f2s(bb.x); pk[5]=f2s(bb.y); pk[6]=f2s(bb.z); pk[7]=f2s(bb.w);
      int el = (n*64 + kc*8) ^ ((n&7)<<3);
      *reinterpret_cast<short8*>(&B_s[el]) = pk;
    }
    __syncthreads();
    #pragma unroll
    for(int ks=0; ks<2; ks++){
      short8 af[4], bfr[4];
      #pragma unroll
      for(int fr=0; fr<4; fr++){
        int row = wr*64 + fr*16 + l16;
        int el = (row*64 + ks*32 + l4*8) ^ ((row&7)<<3);
        af[fr] = *reinterpret_cast<const short8*>(&A_s[el]);
      }
      #pragma unroll
      for(int fc=0; fc<4; fc++){
        int n = wc*64 + fc*16 + l16;
        int el = (n*64 + ks*32 + l4*8) ^ ((n&7)<<3);
        bfr[fc] = *reinterpret_cast<const short8*>(&B_s[el]);
      }
      #pragma unroll
      for(int fr=0; fr<4; fr++)
        #pragma unroll
        for(int fc=0; fc<4; fc++)
          acc[fr][fc] = __builtin_amdgcn_mfma_f32_16x16x32_bf16(af[fr], bfr[fc], acc[fr][fc], 0,0,0);
    }
  }
  // ---- epilogue: bias + store f32
  #pragma unroll
  for(int fr=0; fr<4; fr++){
    #pragma unroll
    for(int fc=0; fc<4; fc++){
      int ocol = o_base + wc*64 + fc*16 + l16;
      float bias = ab[t*CC + ocol];
      #pragma unroll
      for(int r=0; r<4; r++){
        int row = row_base + wr*64 + fr*16 + l4*4 + r;
        out[((size_t)g*HWW + row)*CC + ocol] = acc[fr][fc][r] + bias;
      }
    }
  }
}

// ------------------------------------------------------------------ launch
extern "C" void kernel_launch(void* const* d_in, const int* in_sizes, int n_in,
                              void* d_out, int out_size, void* d_ws, size_t ws_size,
                              hipStream_t stream)
{
  const float* x   = (const float*)d_in[0];
  const int*   mask= (const int*)  d_in[1];
  const float* pe  = (const float*)d_in[2];
  const float* lnw = (const float*)d_in[3];
  const float* lnb = (const float*)d_in[4];
  const float* qw  = (const float*)d_in[5];
  const float* qb  = (const float*)d_in[6];
  const float* kw  = (const float*)d_in[7];
  const float* kb  = (const float*)d_in[8];
  const float* vw  = (const float*)d_in[9];
  const float* vb  = (const float*)d_in[10];
  const float* aw  = (const float*)d_in[11];
  const float* ab  = (const float*)d_in[12];
  const float* ra  = (const float*)d_in[13];
  const float* rm  = (const float*)d_in[14];

  char* ws = (char*)d_ws;
  float* mu    = (float*)ws;                          //   92,160 B
  float* rstd  = (float*)(ws + 92160);                //   92,160 B
  bf16*  W_all = (bf16*) (ws + 184320);               //  1,310,720 B (2x1280x256 bf16)
  float* b_all = (float*)(ws + 1495040);              //     10,240 B
  bf16*  qkvm  = (bf16*) (ws + 1505280);              // 58,982,400 B (23040x1280 bf16)
  bf16*  attn  = (bf16*) (ws + 60487680);             // 11,796,480 B
  float* out   = (float*)d_out;

  hipLaunchKernelGGL(ln_stats_kernel, dim3(NTOK/4), dim3(256), 0, stream, x, mu, rstd);
  hipLaunchKernelGGL(wcomp_kernel, dim3(640), dim3(256), 0, stream,
                     qw, qb, kw, kb, vw, vb, ra, rm, W_all, b_all);
  hipLaunchKernelGGL(qkvm_gemm_kernel, dim3(5, 18, 10), dim3(256), 0, stream,
                     x, pe, mu, rstd, lnw, lnb, W_all, b_all, qkvm);
  hipLaunchKernelGGL(attn_lite_kernel, dim3(BB*HWW), dim3(256), 0, stream,
                     qkvm, pe, mask, attn);
  hipLaunchKernelGGL(out_gemm_kernel, dim3(2, 18, 10), dim3(256), 0, stream,
                     attn, pe, aw, ab, out);
}

// Round 12
// 179.102 us; speedup vs baseline: 1.3385x; 1.3385x over previous
//
#include <hip/hip_runtime.h>
#include <hip/hip_bf16.h>

#define BB 2
#define LL 5
#define HH 48
#define WW 48
#define CC 256
#define MM 8
#define DD 32
#define HWW (HH*WW)        // 2304
#define NTOK (BB*LL*HWW)   // 23040
#define INNER 256
#define NOUT 1280          // qa(512) | k(256) | vm(512)
#define SCALE_ATT 0.17677669529663687f

typedef __hip_bfloat16 bf16;
typedef short short8 __attribute__((ext_vector_type(8)));
typedef short short4v __attribute__((ext_vector_type(4)));
typedef float f32x4  __attribute__((ext_vector_type(4)));

__device__ __forceinline__ float b2f(bf16 v){ return __bfloat162float(v); }
__device__ __forceinline__ bf16 f2b(float v){ return __float2bfloat16(v); }
__device__ __forceinline__ short f2s(float v){
  bf16 h = __float2bfloat16(v);
  return *reinterpret_cast<short*>(&h);
}

// ------------------------------------------------- fused LN stats + apply
// block 256 = 4 tokens x 64 lanes; butterfly reduce gives all lanes m/var;
// writes xn bf16 (bit-identical rounding to the old in-GEMM LN staging).
__global__ __launch_bounds__(256) void ln_fused_kernel(
    const float* __restrict__ x, const float* __restrict__ lnw,
    const float* __restrict__ lnb, bf16* __restrict__ xn)
{
  int tok  = blockIdx.x*4 + (threadIdx.x>>6);
  int lane = threadIdx.x & 63;
  const float4* xr = (const float4*)(x + (size_t)tok*CC);
  float4 v = xr[lane];
  float s  = v.x + v.y + v.z + v.w;
  float sq = v.x*v.x + v.y*v.y + v.z*v.z + v.w*v.w;
  #pragma unroll
  for(int off=32; off>=1; off>>=1){
    s  += __shfl_xor(s,  off, 64);
    sq += __shfl_xor(sq, off, 64);
  }
  float m   = s  * (1.f/CC);
  float var = sq * (1.f/CC) - m*m;
  float rs  = rsqrtf(var + 1e-5f);
  float4 w = *(const float4*)(lnw + lane*4);
  float4 c = *(const float4*)(lnb + lane*4);
  short4v pk;
  pk[0] = f2s((v.x-m)*rs*w.x + c.x);
  pk[1] = f2s((v.y-m)*rs*w.y + c.y);
  pk[2] = f2s((v.z-m)*rs*w.z + c.z);
  pk[3] = f2s((v.w-m)*rs*w.w + c.w);
  *reinterpret_cast<short4v*>(xn + (size_t)tok*CC + lane*4) = pk;
}

// ------------------------------------------------- composite weight build
__global__ __launch_bounds__(256) void wcomp_kernel(
    const float* __restrict__ qw, const float* __restrict__ qb,
    const float* __restrict__ kw, const float* __restrict__ kb,
    const float* __restrict__ vw, const float* __restrict__ vb,
    const float* __restrict__ ra, const float* __restrict__ rm,
    bf16* __restrict__ W_all, float* __restrict__ b_all)
{
  int bid = blockIdx.x;
  int t = bid / 320, nb = bid % 320;
  int tid = threadIdx.x;
  int wv = tid>>6, lane = tid&63;
  int n = nb*4 + wv;

  float a0=0.f,a1=0.f,a2=0.f,a3=0.f, bias=0.f;
  if(n < 512 || n >= 768){
    bool isq = (n < 512);
    int nr = isq ? n : n-768;
    int s = nr>>8, mdp = nr&255, m = mdp>>5, dp = mdp&31;
    int r = isq ? (2*t+s) : (2*s+t);
    const float* rel  = (isq ? ra : rm) + ((size_t)r*MM + m)*DD*DD + dp;     // [p] stride DD
    const float* wrow = (isq ? qw : vw) + (size_t)t*INNER*CC + (size_t)m*DD*CC;
    const float* brow = (isq ? qb : vb) + t*INNER + m*DD;
    #pragma unroll
    for(int p=0;p<DD;p++){
      float rv = rel[p*DD];
      float4 w4 = *(const float4*)(wrow + p*CC + lane*4);
      a0 += w4.x*rv; a1 += w4.y*rv; a2 += w4.z*rv; a3 += w4.w*rv;
      bias += brow[p]*rv;
    }
  } else {
    int o = n - 512;
    float4 w4 = *(const float4*)(kw + (size_t)t*INNER*CC + (size_t)o*CC + lane*4);
    a0=w4.x; a1=w4.y; a2=w4.z; a3=w4.w;
    bias = kb[t*INNER + o];
  }
  bf16* dst = W_all + ((size_t)t*NOUT + n)*CC + lane*4;
  dst[0]=f2b(a0); dst[1]=f2b(a1); dst[2]=f2b(a2); dst[3]=f2b(a3);
  if(lane==0) b_all[t*NOUT + n] = bias;
}

// ------------------------------------------------------------ qa/k/vm GEMM (MFMA)
// grid (10, 18, 10): x = 128-col tile of 1280, y = 128-row tile, z = (b,l)
// A (xn bf16) and B (W_all bf16) both staged as plain short8 copies.
__global__ __launch_bounds__(256) void qkvm_gemm_kernel(
    const bf16* __restrict__ xn,  const float* __restrict__ pe,
    const bf16* __restrict__ W_all, const float* __restrict__ b_all,
    bf16* __restrict__ qkvm)
{
  int g = blockIdx.z;
  int t = (int)pe[(size_t)g*HWW*3 + 2];
  int o_base = blockIdx.x * 128;
  const bf16*  wsel = W_all + ((size_t)t*NOUT + o_base)*CC;
  const float* bsel = b_all + t*NOUT;
  int row_base = blockIdx.y*128;
  int tid = threadIdx.x;
  int tokbase = g*HWW + row_base;

  __shared__ __align__(16) short A_s[128*64];
  __shared__ __align__(16) short B_s[128*64];

  int wv = tid>>6, lane = tid&63;
  int wr = wv>>1, wc = wv&1;
  int l16 = lane&15, l4 = lane>>4;
  int kc = tid & 7;            // fixed k-chunk (8 elems) for staging
  int rsub = tid >> 3;         // 0..31

  f32x4 acc[4][4];
  #pragma unroll
  for(int i=0;i<4;i++)
    #pragma unroll
    for(int j=0;j<4;j++) acc[i][j] = (f32x4){0.f,0.f,0.f,0.f};

  for(int kk=0; kk<CC; kk+=64){
    if(kk) __syncthreads();
    // ---- stage A (xn bf16, direct 16B copy), swizzled
    #pragma unroll
    for(int tt=0; tt<4; tt++){
      int row = rsub + tt*32;
      short8 pk = *reinterpret_cast<const short8*>(
          xn + (size_t)(tokbase + row)*CC + kk + kc*8);
      int el = (row*64 + kc*8) ^ ((row&7)<<3);
      *reinterpret_cast<short8*>(&A_s[el]) = pk;
    }
    // ---- stage B (bf16 composite weights, direct copy), swizzled
    #pragma unroll
    for(int tt=0; tt<4; tt++){
      int n = rsub + tt*32;
      short8 pk = *reinterpret_cast<const short8*>(wsel + (size_t)n*CC + kk + kc*8);
      int el = (n*64 + kc*8) ^ ((n&7)<<3);
      *reinterpret_cast<short8*>(&B_s[el]) = pk;
    }
    __syncthreads();
    // ---- 2 x k32 MFMA rounds
    #pragma unroll
    for(int ks=0; ks<2; ks++){
      short8 af[4], bfr[4];
      #pragma unroll
      for(int fr=0; fr<4; fr++){
        int row = wr*64 + fr*16 + l16;
        int el = (row*64 + ks*32 + l4*8) ^ ((row&7)<<3);
        af[fr] = *reinterpret_cast<const short8*>(&A_s[el]);
      }
      #pragma unroll
      for(int fc=0; fc<4; fc++){
        int n = wc*64 + fc*16 + l16;
        int el = (n*64 + ks*32 + l4*8) ^ ((n&7)<<3);
        bfr[fc] = *reinterpret_cast<const short8*>(&B_s[el]);
      }
      #pragma unroll
      for(int fr=0; fr<4; fr++)
        #pragma unroll
        for(int fc=0; fc<4; fc++)
          acc[fr][fc] = __builtin_amdgcn_mfma_f32_16x16x32_bf16(af[fr], bfr[fc], acc[fr][fc], 0,0,0);
    }
  }
  // ---- epilogue: bias + store bf16
  #pragma unroll
  for(int fr=0; fr<4; fr++){
    #pragma unroll
    for(int fc=0; fc<4; fc++){
      int ocol = o_base + wc*64 + fc*16 + l16;
      float bias = bsel[ocol];
      #pragma unroll
      for(int r=0; r<4; r++){
        int row = row_base + wr*64 + fr*16 + l4*4 + r;
        qkvm[((size_t)g*HWW + row)*NOUT + ocol] = f2b(acc[fr][fc][r] + bias);
      }
    }
  }
}

// ------------------------------------------------------------ attention lite
// grid = B*HWW = 4608 blocks; block 256 thr; half-wave (32 lanes = d) = one head.
__global__ __launch_bounds__(256) void attn_lite_kernel(
    const bf16* __restrict__ qkvm, const float* __restrict__ pe,
    const int*  __restrict__ mask, bf16* __restrict__ attn_out)
{
  int pix = blockIdx.x;
  int b = pix / HWW, hw = pix - b*HWW;
  int tid = threadIdx.x;
  int m = tid>>5, d = tid&31;

  __shared__ int st[LL];
  __shared__ unsigned mbS;
  if(tid==0) mbS = 0u;
  if(tid<LL) st[tid] = (int)pe[(size_t)(b*LL+tid)*HWW*3 + 2];
  __syncthreads();
  const int* mrow = mask + ((size_t)b*HWW + hw)*25;
  if(tid<25 && mrow[tid]==0) atomicOr(&mbS, 1u<<tid);
  __syncthreads();
  unsigned mb = mbS;

  float qa[LL][2], kv[LL], vm[LL][2];
  #pragma unroll
  for(int l=0;l<LL;l++){
    size_t base = ((size_t)(b*LL+l)*HWW + hw)*NOUT + m*DD + d;
    qa[l][0] = b2f(qkvm[base]);
    qa[l][1] = b2f(qkvm[base+256]);
    kv[l]    = b2f(qkvm[base+512]);
    vm[l][0] = b2f(qkvm[base+768]);
    vm[l][1] = b2f(qkvm[base+1024]);
  }

  float p[LL][LL];
  #pragma unroll
  for(int i=0;i<LL;i++){
    #pragma unroll
    for(int j=0;j<LL;j++){
      int stj = st[j];
      float part = (stj ? qa[i][1] : qa[i][0]) * kv[j];
      #pragma unroll
      for(int off=16; off>=1; off>>=1) part += __shfl_xor(part, off, 32);
      p[i][j] = (mb & (1u<<(i*5+j))) ? -1e9f : part*SCALE_ATT;
    }
  }
  #pragma unroll
  for(int i=0;i<LL;i++){
    float mx = p[i][0];
    #pragma unroll
    for(int j=1;j<LL;j++) mx = fmaxf(mx, p[i][j]);
    float ssum = 0.f;
    #pragma unroll
    for(int j=0;j<LL;j++){ p[i][j] = __expf(p[i][j]-mx); ssum += p[i][j]; }
    float inv = 1.f/ssum;
    int sti = st[i];
    float o = 0.f;
    #pragma unroll
    for(int j=0;j<LL;j++) o += p[i][j] * (sti ? vm[j][1] : vm[j][0]);
    o *= inv;
    attn_out[(((size_t)b*HWW + hw)*LL + i)*CC + m*DD + d] = f2b(o);
  }
}

// ------------------------------------------------------- output projection (MFMA)
// grid (2, 18, 10): x = 128-col tile, y = 128-row tile, z = (b,l)
__global__ __launch_bounds__(256) void out_gemm_kernel(
    const bf16* __restrict__ attn_out, const float* __restrict__ pe,
    const float* __restrict__ aw, const float* __restrict__ ab,
    float* __restrict__ out)
{
  int g = blockIdx.z; int b = g/LL, l = g%LL;
  int t = (int)pe[(size_t)g*HWW*3 + 2];
  int o_base = blockIdx.x*128;
  int row_base = blockIdx.y*128;
  int tid = threadIdx.x;
  const float* wsel = aw + ((size_t)t*CC + o_base)*CC;

  __shared__ __align__(16) short A_s[128*64];
  __shared__ __align__(16) short B_s[128*64];

  int wv = tid>>6, lane = tid&63;
  int wr = wv>>1, wc = wv&1;
  int l16 = lane&15, l4 = lane>>4;
  int kc = tid & 7;
  int rsub = tid >> 3;

  f32x4 acc[4][4];
  #pragma unroll
  for(int i=0;i<4;i++)
    #pragma unroll
    for(int j=0;j<4;j++) acc[i][j] = (f32x4){0.f,0.f,0.f,0.f};

  for(int kk=0; kk<CC; kk+=64){
    if(kk) __syncthreads();
    // ---- stage A (bf16 source, direct 16B copy), swizzled
    #pragma unroll
    for(int tt=0; tt<4; tt++){
      int row = rsub + tt*32;
      short8 pk = *reinterpret_cast<const short8*>(
          attn_out + (((size_t)(b*HWW) + row_base + row)*LL + l)*CC + kk + kc*8);
      int el = (row*64 + kc*8) ^ ((row&7)<<3);
      *reinterpret_cast<short8*>(&A_s[el]) = pk;
    }
    // ---- stage B (weights f32 -> bf16), swizzled
    #pragma unroll
    for(int tt=0; tt<4; tt++){
      int n = rsub + tt*32;
      const float4* src = (const float4*)(wsel + (size_t)n*CC + kk + kc*8);
      float4 ba = src[0], bb = src[1];
      short8 pk;
      pk[0]=f2s(ba.x); pk[1]=f2s(ba.y); pk[2]=f2s(ba.z); pk[3]=f2s(ba.w);
      pk[4]=f2s(bb.x); pk[5]=f2s(bb.y); pk[6]=f2s(bb.z); pk[7]=f2s(bb.w);
      int el = (n*64 + kc*8) ^ ((n&7)<<3);
      *reinterpret_cast<short8*>(&B_s[el]) = pk;
    }
    __syncthreads();
    #pragma unroll
    for(int ks=0; ks<2; ks++){
      short8 af[4], bfr[4];
      #pragma unroll
      for(int fr=0; fr<4; fr++){
        int row = wr*64 + fr*16 + l16;
        int el = (row*64 + ks*32 + l4*8) ^ ((row&7)<<3);
        af[fr] = *reinterpret_cast<const short8*>(&A_s[el]);
      }
      #pragma unroll
      for(int fc=0; fc<4; fc++){
        int n = wc*64 + fc*16 + l16;
        int el = (n*64 + ks*32 + l4*8) ^ ((n&7)<<3);
        bfr[fc] = *reinterpret_cast<const short8*>(&B_s[el]);
      }
      #pragma unroll
      for(int fr=0; fr<4; fr++)
        #pragma unroll
        for(int fc=0; fc<4; fc++)
          acc[fr][fc] = __builtin_amdgcn_mfma_f32_16x16x32_bf16(af[fr], bfr[fc], acc[fr][fc], 0,0,0);
    }
  }
  // ---- epilogue: bias + store f32
  #pragma unroll
  for(int fr=0; fr<4; fr++){
    #pragma unroll
    for(int fc=0; fc<4; fc++){
      int ocol = o_base + wc*64 + fc*16 + l16;
      float bias = ab[t*CC + ocol];
      #pragma unroll
      for(int r=0; r<4; r++){
        int row = row_base + wr*64 + fr*16 + l4*4 + r;
        out[((size_t)g*HWW + row)*CC + ocol] = acc[fr][fc][r] + bias;
      }
    }
  }
}

// ------------------------------------------------------------------ launch
extern "C" void kernel_launch(void* const* d_in, const int* in_sizes, int n_in,
                              void* d_out, int out_size, void* d_ws, size_t ws_size,
                              hipStream_t stream)
{
  const float* x   = (const float*)d_in[0];
  const int*   mask= (const int*)  d_in[1];
  const float* pe  = (const float*)d_in[2];
  const float* lnw = (const float*)d_in[3];
  const float* lnb = (const float*)d_in[4];
  const float* qw  = (const float*)d_in[5];
  const float* qb  = (const float*)d_in[6];
  const float* kw  = (const float*)d_in[7];
  const float* kb  = (const float*)d_in[8];
  const float* vw  = (const float*)d_in[9];
  const float* vb  = (const float*)d_in[10];
  const float* aw  = (const float*)d_in[11];
  const float* ab  = (const float*)d_in[12];
  const float* ra  = (const float*)d_in[13];
  const float* rm  = (const float*)d_in[14];

  // xn and attn alias the same region: xn is dead once qkvm_gemm completes,
  // attn is written strictly after (stream-ordered).
  char* ws = (char*)d_ws;
  bf16*  xn    = (bf16*) ws;                          // 11,796,480 B
  bf16*  attn  = (bf16*) ws;                          // (alias, same size)
  bf16*  W_all = (bf16*) (ws + 11796480);             //  1,310,720 B
  float* b_all = (float*)(ws + 13107200);             //     10,240 B
  bf16*  qkvm  = (bf16*) (ws + 13117440);             // 58,982,400 B
  float* out   = (float*)d_out;                       // total ws: 72.1 MB

  hipLaunchKernelGGL(ln_fused_kernel, dim3(NTOK/4), dim3(256), 0, stream,
                     x, lnw, lnb, xn);
  hipLaunchKernelGGL(wcomp_kernel, dim3(640), dim3(256), 0, stream,
                     qw, qb, kw, kb, vw, vb, ra, rm, W_all, b_all);
  hipLaunchKernelGGL(qkvm_gemm_kernel, dim3(10, 18, 10), dim3(256), 0, stream,
                     xn, pe, W_all, b_all, qkvm);
  hipLaunchKernelGGL(attn_lite_kernel, dim3(BB*HWW), dim3(256), 0, stream,
                     qkvm, pe, mask, attn);
  hipLaunchKernelGGL(out_gemm_kernel, dim3(2, 18, 10), dim3(256), 0, stream,
                     attn, pe, aw, ab, out);
}

// Round 14
// 173.324 us; speedup vs baseline: 1.3831x; 1.0333x over previous
//
#include <hip/hip_runtime.h>
#include <hip/hip_bf16.h>

#define BB 2
#define LL 5
#define HH 48
#define WW 48
#define CC 256
#define MM 8
#define DD 32
#define HWW (HH*WW)        // 2304
#define NTOK (BB*LL*HWW)   // 23040
#define INNER 256
#define NOUT 1280          // qa(512) | k(256) | vm(512)
#define SCALE_ATT 0.17677669529663687f

typedef __hip_bfloat16 bf16;
typedef short short8 __attribute__((ext_vector_type(8)));
typedef short short4v __attribute__((ext_vector_type(4)));
typedef float f32x4  __attribute__((ext_vector_type(4)));
typedef unsigned int u32;
typedef const __attribute__((address_space(1))) u32* gp32;
typedef __attribute__((address_space(3))) u32* lp32;

__device__ __forceinline__ float b2f(bf16 v){ return __bfloat162float(v); }
__device__ __forceinline__ bf16 f2b(float v){ return __float2bfloat16(v); }
__device__ __forceinline__ short f2s(float v){
  bf16 h = __float2bfloat16(v);
  return *reinterpret_cast<short*>(&h);
}
// async global->LDS, 16B per lane; lds dst = wave-uniform base + lane*16
__device__ __forceinline__ void gload16(const void* g, void* l){
  __builtin_amdgcn_global_load_lds((gp32)g, (lp32)l, 16, 0, 0);
}

// ------------------------------------------------- fused LN stats + apply
__global__ __launch_bounds__(256) void ln_fused_kernel(
    const float* __restrict__ x, const float* __restrict__ lnw,
    const float* __restrict__ lnb, bf16* __restrict__ xn)
{
  int tok  = blockIdx.x*4 + (threadIdx.x>>6);
  int lane = threadIdx.x & 63;
  const float4* xr = (const float4*)(x + (size_t)tok*CC);
  float4 v = xr[lane];
  float s  = v.x + v.y + v.z + v.w;
  float sq = v.x*v.x + v.y*v.y + v.z*v.z + v.w*v.w;
  #pragma unroll
  for(int off=32; off>=1; off>>=1){
    s  += __shfl_xor(s,  off, 64);
    sq += __shfl_xor(sq, off, 64);
  }
  float m   = s  * (1.f/CC);
  float var = sq * (1.f/CC) - m*m;
  float rs  = rsqrtf(var + 1e-5f);
  float4 w = *(const float4*)(lnw + lane*4);
  float4 c = *(const float4*)(lnb + lane*4);
  short4v pk;
  pk[0] = f2s((v.x-m)*rs*w.x + c.x);
  pk[1] = f2s((v.y-m)*rs*w.y + c.y);
  pk[2] = f2s((v.z-m)*rs*w.z + c.z);
  pk[3] = f2s((v.w-m)*rs*w.w + c.w);
  *reinterpret_cast<short4v*>(xn + (size_t)tok*CC + lane*4) = pk;
}

// ------------------------------------------------- composite weight build
// also casts aw (f32) -> aw_bf (bf16) so out_gemm B-stage is a plain copy
__global__ __launch_bounds__(256) void wcomp_kernel(
    const float* __restrict__ qw, const float* __restrict__ qb,
    const float* __restrict__ kw, const float* __restrict__ kb,
    const float* __restrict__ vw, const float* __restrict__ vb,
    const float* __restrict__ ra, const float* __restrict__ rm,
    const float* __restrict__ aw, bf16* __restrict__ aw_bf,
    bf16* __restrict__ W_all, float* __restrict__ b_all)
{
  int bid = blockIdx.x;
  int tid = threadIdx.x;
  {  // aw cast: 2*256*256 = 131072 elems over 640x256 threads
    int idx = bid*256 + tid;
    if(idx < 2*CC*CC) aw_bf[idx] = f2b(aw[idx]);
  }
  int t = bid / 320, nb = bid % 320;
  int wv = tid>>6, lane = tid&63;
  int n = nb*4 + wv;

  float a0=0.f,a1=0.f,a2=0.f,a3=0.f, bias=0.f;
  if(n < 512 || n >= 768){
    bool isq = (n < 512);
    int nr = isq ? n : n-768;
    int s = nr>>8, mdp = nr&255, m = mdp>>5, dp = mdp&31;
    int r = isq ? (2*t+s) : (2*s+t);
    const float* rel  = (isq ? ra : rm) + ((size_t)r*MM + m)*DD*DD + dp;     // [p] stride DD
    const float* wrow = (isq ? qw : vw) + (size_t)t*INNER*CC + (size_t)m*DD*CC;
    const float* brow = (isq ? qb : vb) + t*INNER + m*DD;
    #pragma unroll
    for(int p=0;p<DD;p++){
      float rv = rel[p*DD];
      float4 w4 = *(const float4*)(wrow + p*CC + lane*4);
      a0 += w4.x*rv; a1 += w4.y*rv; a2 += w4.z*rv; a3 += w4.w*rv;
      bias += brow[p]*rv;
    }
  } else {
    int o = n - 512;
    float4 w4 = *(const float4*)(kw + (size_t)t*INNER*CC + (size_t)o*CC + lane*4);
    a0=w4.x; a1=w4.y; a2=w4.z; a3=w4.w;
    bias = kb[t*INNER + o];
  }
  bf16* dst = W_all + ((size_t)t*NOUT + n)*CC + lane*4;
  dst[0]=f2b(a0); dst[1]=f2b(a1); dst[2]=f2b(a2); dst[3]=f2b(a3);
  if(lane==0) b_all[t*NOUT + n] = bias;
}

// ------------------------------------------------------------ qa/k/vm GEMM (MFMA)
// grid (10, 18, 10). Staging via global_load_lds (linear LDS dest,
// pre-swizzled per-lane global source; read side keeps the XOR swizzle).
__global__ __launch_bounds__(256) void qkvm_gemm_kernel(
    const bf16* __restrict__ xn,  const float* __restrict__ pe,
    const bf16* __restrict__ W_all, const float* __restrict__ b_all,
    bf16* __restrict__ qkvm)
{
  int g = blockIdx.z;
  int t = (int)pe[(size_t)g*HWW*3 + 2];
  int o_base = blockIdx.x * 128;
  const bf16*  wsel = W_all + ((size_t)t*NOUT + o_base)*CC;
  const float* bsel = b_all + t*NOUT;
  int row_base = blockIdx.y*128;
  int tid = threadIdx.x;
  int tokbase = g*HWW + row_base;

  __shared__ __align__(16) short A_s[128*64];
  __shared__ __align__(16) short B_s[128*64];

  int wv = tid>>6, lane = tid&63;
  int wr = wv>>1, wc = wv&1;
  int l16 = lane&15, l4 = lane>>4;
  int lr = lane>>3;            // row within 8-row staging group
  int sw = (lane&7) ^ lr;      // pre-swizzled source 16B-chunk

  f32x4 acc[4][4];
  #pragma unroll
  for(int i=0;i<4;i++)
    #pragma unroll
    for(int j=0;j<4;j++) acc[i][j] = (f32x4){0.f,0.f,0.f,0.f};

  for(int kk=0; kk<CC; kk+=64){
    if(kk) __syncthreads();
    // ---- stage A & B via async global->LDS (4 calls each per wave)
    #pragma unroll
    for(int i=0;i<4;i++){
      int ci  = wv*4 + i;           // 16B-chunk group: 64 chunks = 8 rows
      int row = ci*8 + lr;
      gload16(xn  + (size_t)(tokbase + row)*CC + kk + sw*8, &A_s[ci*512]);
      gload16(wsel + (size_t)row*CC          + kk + sw*8, &B_s[ci*512]);
    }
    __syncthreads();
    // ---- 2 x k32 MFMA rounds
    #pragma unroll
    for(int ks=0; ks<2; ks++){
      short8 af[4], bfr[4];
      #pragma unroll
      for(int fr=0; fr<4; fr++){
        int row = wr*64 + fr*16 + l16;
        int el = (row*64 + ks*32 + l4*8) ^ ((row&7)<<3);
        af[fr] = *reinterpret_cast<const short8*>(&A_s[el]);
      }
      #pragma unroll
      for(int fc=0; fc<4; fc++){
        int n = wc*64 + fc*16 + l16;
        int el = (n*64 + ks*32 + l4*8) ^ ((n&7)<<3);
        bfr[fc] = *reinterpret_cast<const short8*>(&B_s[el]);
      }
      #pragma unroll
      for(int fr=0; fr<4; fr++)
        #pragma unroll
        for(int fc=0; fc<4; fc++)
          acc[fr][fc] = __builtin_amdgcn_mfma_f32_16x16x32_bf16(af[fr], bfr[fc], acc[fr][fc], 0,0,0);
    }
  }
  // ---- epilogue: bias + store bf16
  #pragma unroll
  for(int fr=0; fr<4; fr++){
    #pragma unroll
    for(int fc=0; fc<4; fc++){
      int ocol = o_base + wc*64 + fc*16 + l16;
      float bias = bsel[ocol];
      #pragma unroll
      for(int r=0; r<4; r++){
        int row = row_base + wr*64 + fr*16 + l4*4 + r;
        qkvm[((size_t)g*HWW + row)*NOUT + ocol] = f2b(acc[fr][fc][r] + bias);
      }
    }
  }
}

// ------------------------------------------------------------ attention lite
// grid = B*HWW = 4608 blocks; block 256 thr; half-wave (32 lanes = d) = one head.
__global__ __launch_bounds__(256) void attn_lite_kernel(
    const bf16* __restrict__ qkvm, const float* __restrict__ pe,
    const int*  __restrict__ mask, bf16* __restrict__ attn_out)
{
  int pix = blockIdx.x;
  int b = pix / HWW, hw = pix - b*HWW;
  int tid = threadIdx.x;
  int m = tid>>5, d = tid&31;

  __shared__ int st[LL];
  __shared__ unsigned mbS;
  if(tid==0) mbS = 0u;
  if(tid<LL) st[tid] = (int)pe[(size_t)(b*LL+tid)*HWW*3 + 2];
  __syncthreads();
  const int* mrow = mask + ((size_t)b*HWW + hw)*25;
  if(tid<25 && mrow[tid]==0) atomicOr(&mbS, 1u<<tid);
  __syncthreads();
  unsigned mb = mbS;

  float qa[LL][2], kv[LL], vm[LL][2];
  #pragma unroll
  for(int l=0;l<LL;l++){
    size_t base = ((size_t)(b*LL+l)*HWW + hw)*NOUT + m*DD + d;
    qa[l][0] = b2f(qkvm[base]);
    qa[l][1] = b2f(qkvm[base+256]);
    kv[l]    = b2f(qkvm[base+512]);
    vm[l][0] = b2f(qkvm[base+768]);
    vm[l][1] = b2f(qkvm[base+1024]);
  }

  float p[LL][LL];
  #pragma unroll
  for(int i=0;i<LL;i++){
    #pragma unroll
    for(int j=0;j<LL;j++){
      int stj = st[j];
      float part = (stj ? qa[i][1] : qa[i][0]) * kv[j];
      #pragma unroll
      for(int off=16; off>=1; off>>=1) part += __shfl_xor(part, off, 32);
      p[i][j] = (mb & (1u<<(i*5+j))) ? -1e9f : part*SCALE_ATT;
    }
  }
  #pragma unroll
  for(int i=0;i<LL;i++){
    float mx = p[i][0];
    #pragma unroll
    for(int j=1;j<LL;j++) mx = fmaxf(mx, p[i][j]);
    float ssum = 0.f;
    #pragma unroll
    for(int j=0;j<LL;j++){ p[i][j] = __expf(p[i][j]-mx); ssum += p[i][j]; }
    float inv = 1.f/ssum;
    int sti = st[i];
    float o = 0.f;
    #pragma unroll
    for(int j=0;j<LL;j++) o += p[i][j] * (sti ? vm[j][1] : vm[j][0]);
    o *= inv;
    attn_out[(((size_t)b*HWW + hw)*LL + i)*CC + m*DD + d] = f2b(o);
  }
}

// ------------------------------------------------------- output projection (MFMA)
// grid (2, 18, 10). Same async-staging scheme; B from pre-cast aw_bf.
__global__ __launch_bounds__(256) void out_gemm_kernel(
    const bf16* __restrict__ attn_out, const float* __restrict__ pe,
    const bf16* __restrict__ aw_bf, const float* __restrict__ ab,
    float* __restrict__ out)
{
  int g = blockIdx.z; int b = g/LL, l = g%LL;
  int t = (int)pe[(size_t)g*HWW*3 + 2];
  int o_base = blockIdx.x*128;
  int row_base = blockIdx.y*128;
  int tid = threadIdx.x;
  const bf16* wsel = aw_bf + ((size_t)t*CC + o_base)*CC;

  __shared__ __align__(16) short A_s[128*64];
  __shared__ __align__(16) short B_s[128*64];

  int wv = tid>>6, lane = tid&63;
  int wr = wv>>1, wc = wv&1;
  int l16 = lane&15, l4 = lane>>4;
  int lr = lane>>3;
  int sw = (lane&7) ^ lr;

  f32x4 acc[4][4];
  #pragma unroll
  for(int i=0;i<4;i++)
    #pragma unroll
    for(int j=0;j<4;j++) acc[i][j] = (f32x4){0.f,0.f,0.f,0.f};

  for(int kk=0; kk<CC; kk+=64){
    if(kk) __syncthreads();
    #pragma unroll
    for(int i=0;i<4;i++){
      int ci  = wv*4 + i;
      int row = ci*8 + lr;
      gload16(attn_out + (((size_t)(b*HWW) + row_base + row)*LL + l)*CC + kk + sw*8,
              &A_s[ci*512]);
      gload16(wsel + (size_t)row*CC + kk + sw*8, &B_s[ci*512]);
    }
    __syncthreads();
    #pragma unroll
    for(int ks=0; ks<2; ks++){
      short8 af[4], bfr[4];
      #pragma unroll
      for(int fr=0; fr<4; fr++){
        int row = wr*64 + fr*16 + l16;
        int el = (row*64 + ks*32 + l4*8) ^ ((row&7)<<3);
        af[fr] = *reinterpret_cast<const short8*>(&A_s[el]);
      }
      #pragma unroll
      for(int fc=0; fc<4; fc++){
        int n = wc*64 + fc*16 + l16;
        int el = (n*64 + ks*32 + l4*8) ^ ((n&7)<<3);
        bfr[fc] = *reinterpret_cast<const short8*>(&B_s[el]);
      }
      #pragma unroll
      for(int fr=0; fr<4; fr++)
        #pragma unroll
        for(int fc=0; fc<4; fc++)
          acc[fr][fc] = __builtin_amdgcn_mfma_f32_16x16x32_bf16(af[fr], bfr[fc], acc[fr][fc], 0,0,0);
    }
  }
  // ---- epilogue: bias + store f32
  #pragma unroll
  for(int fr=0; fr<4; fr++){
    #pragma unroll
    for(int fc=0; fc<4; fc++){
      int ocol = o_base + wc*64 + fc*16 + l16;
      float bias = ab[t*CC + ocol];
      #pragma unroll
      for(int r=0; r<4; r++){
        int row = row_base + wr*64 + fr*16 + l4*4 + r;
        out[((size_t)g*HWW + row)*CC + ocol] = acc[fr][fc][r] + bias;
      }
    }
  }
}

// ------------------------------------------------------------------ launch
extern "C" void kernel_launch(void* const* d_in, const int* in_sizes, int n_in,
                              void* d_out, int out_size, void* d_ws, size_t ws_size,
                              hipStream_t stream)
{
  const float* x   = (const float*)d_in[0];
  const int*   mask= (const int*)  d_in[1];
  const float* pe  = (const float*)d_in[2];
  const float* lnw = (const float*)d_in[3];
  const float* lnb = (const float*)d_in[4];
  const float* qw  = (const float*)d_in[5];
  const float* qb  = (const float*)d_in[6];
  const float* kw  = (const float*)d_in[7];
  const float* kb  = (const float*)d_in[8];
  const float* vw  = (const float*)d_in[9];
  const float* vb  = (const float*)d_in[10];
  const float* aw  = (const float*)d_in[11];
  const float* ab  = (const float*)d_in[12];
  const float* ra  = (const float*)d_in[13];
  const float* rm  = (const float*)d_in[14];

  // xn and attn alias the same region (xn dead before attn is written).
  char* ws = (char*)d_ws;
  bf16*  xn    = (bf16*) ws;                          // 11,796,480 B
  bf16*  attn  = (bf16*) ws;                          // (alias)
  bf16*  W_all = (bf16*) (ws + 11796480);             //  1,310,720 B
  float* b_all = (float*)(ws + 13107200);             //     10,240 B
  bf16*  qkvm  = (bf16*) (ws + 13117440);             // 58,982,400 B
  bf16*  aw_bf = (bf16*) (ws + 72099840);             //    262,144 B
  float* out   = (float*)d_out;                       // total ws: 72.4 MB

  hipLaunchKernelGGL(ln_fused_kernel, dim3(NTOK/4), dim3(256), 0, stream,
                     x, lnw, lnb, xn);
  hipLaunchKernelGGL(wcomp_kernel, dim3(640), dim3(256), 0, stream,
                     qw, qb, kw, kb, vw, vb, ra, rm, aw, aw_bf, W_all, b_all);
  hipLaunchKernelGGL(qkvm_gemm_kernel, dim3(10, 18, 10), dim3(256), 0, stream,
                     xn, pe, W_all, b_all, qkvm);
  hipLaunchKernelGGL(attn_lite_kernel, dim3(BB*HWW), dim3(256), 0, stream,
                     qkvm, pe, mask, attn);
  hipLaunchKernelGGL(out_gemm_kernel, dim3(2, 18, 10), dim3(256), 0, stream,
                     attn, pe, aw_bf, ab, out);
}